// Round 4
// baseline (2488.889 us; speedup 1.0000x reference)
//
#include <hip/hip_runtime.h>
#include <stdint.h>

// Problem constants
#define B_   8
#define N_   32768
#define C_   32
#define K_   22
#define CAT_ 40

typedef unsigned short u16;
typedef unsigned int   u32;

typedef __attribute__((ext_vector_type(8))) short bf16x8;
typedef __attribute__((ext_vector_type(4))) float f32x4;

#define MFMA(a, b, c) __builtin_amdgcn_mfma_f32_16x16x32_bf16(a, b, c, 0, 0, 0)

// ---------- bf16 helpers (raw bits) ----------
__device__ __forceinline__ float b2f(u16 v) { return __uint_as_float(((u32)v) << 16); }
__device__ __forceinline__ u16 f2b(float f) {
    u32 x = __float_as_uint(f);
    return (u16)((x + 0x7fffu + ((x >> 16) & 1u)) >> 16);   // RNE
}
__device__ __forceinline__ u32 pk2(float a, float b) {
    return (u32)f2b(a) | ((u32)f2b(b) << 16);
}

// ---------- packed MFMA A-fragment weight offsets (u16 units) ----------
// layout: idx = ((tile*KB + kb)*64 + lane)*8 ; element = W[tile*16+(lane&15)][kb*32+(lane>>4)*8+j]
#define PK_WIN 0         // 256x32(pad), KB=1 : 8192
#define PK_W1  8192      // 2 x 64x256, KB=8  : 16384 each
#define PK_W2  40960     // 2 x 128x64, KB=2  : 8192 each
#define PK_W3  57344     // 2 x 128x128, KB=4 : 16384 each
#define PK_WC1 90112     // 2 x 128x128       : 16384 each
#define PK_WC2 122880    // 2 x 256x128, KB=4 : 32768 each
#define PK_WC3 188416    // 2 x 32x256, KB=8  : 8192 each
#define PK_WO1 204800    // 128x256, KB=8     : 32768
#define PK_WO2 237568    // 128x128, KB=4     : 16384

// ---------- fp32 bias block offsets (floats) ----------
#define OBIN 0
#define OB1  256
#define OB2  384
#define OB3  640
#define OBC1 896
#define OBC2 1152
#define OBC3 1664
#define OBO1 1728
#define OBO2 1856
#define ODB1 1984
#define ODB2 2240
#define ODB3 2496

// ---------- canonical bf16 dense-head weights (u16 offsets) ----------
#define ODW1 0
#define ODW2 32768
#define ODW3 98304

// ---------- segment accumulator geometry ----------
#define SEGW 164                 // 164 dwords/cluster: 4 mod 32 -> bank spread
#define SEGSZ (32 * SEGW)        // 5248 ints per batch

// ---------- workspace byte offsets ----------
#define OFS_WPK   0u
#define OFS_BIAS  524288u
#define OFS_DWC   540672u
#define OFS_MODE  786432u
#define OFS_FEATC 1048576u          // 11,534,336 B
#define OFS_GACC0 12582912u
#define OFS_GACC1 (OFS_GACC0 + 4u*SEGSZ*8u)   // +167,936
#define OFS_GNET  (OFS_GACC1 + 4u*SEGSZ*8u)
#define GACC_ZERO_BYTES (4u*SEGSZ*8u*2u + 4096u)
#define OFS_CF20  13107200u
#define OFS_CF21  13238272u
#define OFS_F0    16777216u
#define OFS_F1    83886080u
// end = 150,994,944 bytes

// ---------- dtype sniffer ----------
__global__ void kSniff(const u16* __restrict__ featAny, int* __restrict__ mode) {
    __shared__ int cnt;
    if (threadIdx.x == 0) cnt = 0;
    __syncthreads();
    int weird = 0;
    for (int j = 0; j < 4; ++j) {
        u16 v = featAny[threadIdx.x * 4 + j];
        float f = b2f(v);
        if (v == 0 || !(fabsf(f) < 1e10f)) weird++;
    }
    if (weird) atomicAdd(&cnt, weird);
    __syncthreads();
    if (threadIdx.x == 0) *mode = (cnt > 64) ? 1 : 0;
}

__device__ __forceinline__ float fetchF(const void* src, size_t i, int mode) {
    return mode ? ((const float*)src)[i] : b2f(((const u16*)src)[i]);
}

// ---------- weight pack: (COUT,CIN) -> MFMA A-fragment bf16 order ----------
__device__ void packA(const void* __restrict__ src, u16* __restrict__ dst,
                      int COUT, int CIN, int mode, int tid, int np) {
    int KB = (CIN + 31) / 32;
    int tiles = COUT / 16;
    int tot = tiles * KB * 64 * 8;
    for (int i = tid; i < tot; i += np) {
        int j = i & 7;
        int L = (i >> 3) & 63;
        int rest = i >> 9;
        int kb = rest % KB, tile = rest / KB;
        int co = tile * 16 + (L & 15);
        int ci = kb * 32 + (L >> 4) * 8 + j;
        float v = (ci < CIN) ? fetchF(src, (size_t)co * CIN + ci, mode) : 0.f;
        dst[i] = f2b(v);
    }
}

__device__ void cvtF(const void* __restrict__ src, float* __restrict__ dst,
                     int n, int mode, int tid, int np) {
    for (int i = tid; i < n; i += np) dst[i] = fetchF(src, i, mode);
}

__device__ void cvtB(const void* __restrict__ src, u16* __restrict__ dst,
                     int n, int mode, int tid, int np) {
    for (int i = tid; i < n; i += np)
        dst[i] = mode ? f2b(((const float*)src)[i]) : ((const u16*)src)[i];
}

__global__ void kPrep(const void* feat, const void* w_in, const void* b_in,
                      const void* w1, const void* b1, const void* w2, const void* b2,
                      const void* w3, const void* b3,
                      const void* wc1, const void* bc1, const void* wc2, const void* bc2,
                      const void* wc3, const void* bc3,
                      const void* wo1, const void* bo1, const void* wo2, const void* bo2,
                      const void* dw1, const void* db1, const void* dw2, const void* db2,
                      const void* dw3, const void* db3,
                      u16* WPK, float* BIAS, u16* DWC, u16* FEATC,
                      const int* __restrict__ modep) {
    const int mode = *modep;
    int tid = blockIdx.x * blockDim.x + threadIdx.x;
    int np  = gridDim.x * blockDim.x;
    cvtB(feat, FEATC, B_ * N_ * K_, mode, tid, np);
    packA(w_in, WPK + PK_WIN, 256, 22, mode, tid, np);
    packA(w1,                                  WPK + PK_W1,          64, 256, mode, tid, np);
    packA((const u16*)w1 + (mode?32768:16384), WPK + PK_W1 + 16384,  64, 256, mode, tid, np);
    packA(w2,                                  WPK + PK_W2,          128, 64, mode, tid, np);
    packA((const u16*)w2 + (mode?16384:8192),  WPK + PK_W2 + 8192,   128, 64, mode, tid, np);
    packA(w3,                                  WPK + PK_W3,          128, 128, mode, tid, np);
    packA((const u16*)w3 + (mode?32768:16384), WPK + PK_W3 + 16384,  128, 128, mode, tid, np);
    packA(wc1,                                 WPK + PK_WC1,         128, 128, mode, tid, np);
    packA((const u16*)wc1 + (mode?32768:16384),WPK + PK_WC1 + 16384, 128, 128, mode, tid, np);
    packA(wc2,                                 WPK + PK_WC2,         256, 128, mode, tid, np);
    packA((const u16*)wc2 + (mode?65536:32768),WPK + PK_WC2 + 32768, 256, 128, mode, tid, np);
    packA(wc3,                                 WPK + PK_WC3,         32, 256, mode, tid, np);
    packA((const u16*)wc3 + (mode?16384:8192), WPK + PK_WC3 + 8192,  32, 256, mode, tid, np);
    packA(wo1, WPK + PK_WO1, 128, 256, mode, tid, np);
    packA(wo2, WPK + PK_WO2, 128, 128, mode, tid, np);
    cvtF(b_in, BIAS + OBIN, 256, mode, tid, np);
    cvtF(b1,   BIAS + OB1,  128, mode, tid, np);
    cvtF(b2,   BIAS + OB2,  256, mode, tid, np);
    cvtF(b3,   BIAS + OB3,  256, mode, tid, np);
    cvtF(bc1,  BIAS + OBC1, 256, mode, tid, np);
    cvtF(bc2,  BIAS + OBC2, 512, mode, tid, np);
    cvtF(bc3,  BIAS + OBC3, 64,  mode, tid, np);
    cvtF(bo1,  BIAS + OBO1, 128, mode, tid, np);
    cvtF(bo2,  BIAS + OBO2, 128, mode, tid, np);
    cvtF(db1,  BIAS + ODB1, 256, mode, tid, np);
    cvtF(db2,  BIAS + ODB2, 256, mode, tid, np);
    cvtF(db3,  BIAS + ODB3, 40,  mode, tid, np);
    cvtB(dw1, DWC + ODW1, 128 * 256, mode, tid, np);
    cvtB(dw2, DWC + ODW2, 256 * 256, mode, tid, np);
    cvtB(dw3, DWC + ODW3, 256 * 40,  mode, tid, np);
}

// ========== wave-private pipeline building blocks ==========
// scratch: 16 rows x 264 u16 (stride 132 dwords == 4 mod 32 -> balanced banks)
#define SCR_STRIDE 264

template<int TILES, int KB>
__device__ __forceinline__ void mlayer(const u16* __restrict__ wA,
                                       const u16* __restrict__ scr,
                                       int lane, f32x4 (&acc)[TILES]) {
    const int lp = lane & 15, q = lane >> 4;
#pragma unroll
    for (int kb = 0; kb < KB; ++kb) {
        bf16x8 bfrag = *(const bf16x8*)(scr + lp * SCR_STRIDE + kb * 32 + q * 8);
#pragma unroll
        for (int t = 0; t < TILES; ++t) {
            bf16x8 a = *(const bf16x8*)(wA + (size_t)((t * KB + kb) * 64 + lane) * 8);
            acc[t] = MFMA(a, bfrag, acc[t]);
        }
    }
}

template<int TILES>
__device__ __forceinline__ void storeAct(u16* __restrict__ scr, const float* __restrict__ bias,
                                         int lane, f32x4 (&acc)[TILES]) {
    const int lp = lane & 15, q = lane >> 4;
#pragma unroll
    for (int t = 0; t < TILES; ++t) {
        const int co = t * 16 + q * 4;
        f32x4 bv = *(const f32x4*)(bias + co);
        f32x4 v = acc[t];
        *(uint2*)(scr + lp * SCR_STRIDE + co) =
            make_uint2(pk2(fmaxf(v[0] + bv[0], 0.f), fmaxf(v[1] + bv[1], 0.f)),
                       pk2(fmaxf(v[2] + bv[2], 0.f), fmaxf(v[3] + bv[3], 0.f)));
    }
}

template<int TILES>
__device__ __forceinline__ void storeActSeg(u16* __restrict__ scr, const float* __restrict__ bias,
                                            int lane, f32x4 (&acc)[TILES],
                                            int* __restrict__ sSeg, int myclu) {
    const int lp = lane & 15, q = lane >> 4;
#pragma unroll
    for (int t = 0; t < TILES; ++t) {
        const int co = t * 16 + q * 4;
        f32x4 bv = *(const f32x4*)(bias + co);
        f32x4 v = acc[t];
        float r0 = fmaxf(v[0] + bv[0], 0.f), r1 = fmaxf(v[1] + bv[1], 0.f);
        float r2 = fmaxf(v[2] + bv[2], 0.f), r3 = fmaxf(v[3] + bv[3], 0.f);
        *(uint2*)(scr + lp * SCR_STRIDE + co) = make_uint2(pk2(r0, r1), pk2(r2, r3));
        atomicMax(&sSeg[myclu * SEGW + co + 0], __float_as_int(r0));
        atomicMax(&sSeg[myclu * SEGW + co + 1], __float_as_int(r1));
        atomicMax(&sSeg[myclu * SEGW + co + 2], __float_as_int(r2));
        atomicMax(&sSeg[myclu * SEGW + co + 3], __float_as_int(r3));
    }
}

template<int TILES>
__device__ __forceinline__ void corrAtomic(const float* __restrict__ bias, int lane,
                                           f32x4 (&acc)[TILES], int* __restrict__ sSeg, int myclu) {
    const int q = lane >> 4;
#pragma unroll
    for (int t = 0; t < TILES; ++t) {
        const int co = t * 16 + q * 4;
        f32x4 bv = *(const f32x4*)(bias + co);
        f32x4 v = acc[t];
        atomicMax(&sSeg[myclu * SEGW + 128 + co + 0], __float_as_int(fmaxf(v[0] + bv[0], 0.f)));
        atomicMax(&sSeg[myclu * SEGW + 128 + co + 1], __float_as_int(fmaxf(v[1] + bv[1], 0.f)));
        atomicMax(&sSeg[myclu * SEGW + 128 + co + 2], __float_as_int(fmaxf(v[2] + bv[2], 0.f)));
        atomicMax(&sSeg[myclu * SEGW + 128 + co + 3], __float_as_int(fmaxf(v[3] + bv[3], 0.f)));
    }
}

// ---------- iteration-0 fused kernel (barrier-free tiles) ----------
__global__ __launch_bounds__(256)
void kA0(const u16* __restrict__ featc, const int* __restrict__ clu0,
         const u16* __restrict__ WPK, const float* __restrict__ BIAS,
         u32* __restrict__ gF, int* __restrict__ gSeg) {
    __shared__ __attribute__((aligned(16))) u16 sWS[4][16 * SCR_STRIDE];
    __shared__ int sSeg[SEGSZ];
    const int t = threadIdx.x, lane = t & 63, w = t >> 6;
    const int lp = lane & 15;
    const int b = blockIdx.y;
    const size_t bN = (size_t)b * N_;
    u16* scr = sWS[w];
    for (int i = t; i < SEGSZ; i += 256) sSeg[i] = 0;
    __syncthreads();

    for (int s = 0; s < 8; ++s) {
        const int pbase = (blockIdx.x * 8 + s) * 64 + w * 16;
        for (int i = lane; i < 512; i += 64) {
            int pt = i >> 5, k = i & 31;
            scr[pt * SCR_STRIDE + k] = (k < 22) ? featc[(bN + pbase + pt) * 22 + k] : (u16)0;
        }
        const int myclu = clu0[bN + pbase + lp];
        f32x4 a16[16] = {};
        mlayer<16, 1>(WPK + PK_WIN, scr, lane, a16);
        storeAct<16>(scr, BIAS + OBIN, lane, a16);
        f32x4 a4[4] = {};
        mlayer<4, 8>(WPK + PK_W1, scr, lane, a4);
        storeAct<4>(scr, BIAS + OB1, lane, a4);
        f32x4 a8[8] = {};
        mlayer<8, 2>(WPK + PK_W2, scr, lane, a8);
        storeActSeg<8>(scr, BIAS + OB2, lane, a8, sSeg, myclu);
        for (int i = lane; i < 1024; i += 64) {
            int pt = i >> 6, c2 = i & 63;
            gF[(bN + pbase + pt) * 64 + c2] = *(const u32*)(scr + pt * SCR_STRIDE + c2 * 2);
        }
        f32x4 c8[8] = {};
        mlayer<8, 4>(WPK + PK_WC1, scr, lane, c8);
        storeAct<8>(scr, BIAS + OBC1, lane, c8);
        f32x4 c16[16] = {};
        mlayer<16, 4>(WPK + PK_WC2, scr, lane, c16);
        storeAct<16>(scr, BIAS + OBC2, lane, c16);
        f32x4 r2[2] = {};
        mlayer<2, 8>(WPK + PK_WC3, scr, lane, r2);
        corrAtomic<2>(BIAS + OBC3, lane, r2, sSeg, myclu);
    }
    __syncthreads();
    for (int i = t; i < SEGSZ; i += 256) atomicMax(&gSeg[b * SEGSZ + i], sSeg[i]);
}

// ---------- per-batch cluster math: cf2[b][c][ch] ----------
__global__ __launch_bounds__(256)
void kB(const int* __restrict__ gSeg, float* __restrict__ cf2) {
    __shared__ float sA[SEGSZ];
    __shared__ float sR[1024];
    __shared__ float sI[32];
    const int t = threadIdx.x, b = blockIdx.x;
    for (int i = t; i < SEGSZ; i += 256) sA[i] = __int_as_float(gSeg[b * SEGSZ + i]);
    __syncthreads();
    if (t < 32) {
        float s = 0.f;
        for (int j = 0; j < 32; ++j) { float v = sA[t * SEGW + 128 + j]; s = fmaf(v, v, s); }
        sI[t] = 1.f / fmaxf(sqrtf(s), 1e-12f);
    }
    __syncthreads();
    for (int i = t; i < 1024; i += 256) {
        int ca = i >> 5, cb = i & 31;
        float s = 0.f;
        for (int j = 0; j < 32; ++j)
            s = fmaf(sA[ca * SEGW + 128 + j], sA[cb * SEGW + 128 + j], s);
        sR[i] = s * sI[ca] * sI[cb];
    }
    __syncthreads();
    for (int i = t; i < 4096; i += 256) {
        int c = i >> 7, ch = i & 127;
        float s = 0.f;
        for (int cp = 0; cp < 32; ++cp)
            s = fmaf(sA[cp * SEGW + ch], sR[cp * 32 + c], s);
        cf2[((size_t)b * 32 + c) * 128 + ch] = s;
    }
}

// ---------- iteration-1 fused kernel ----------
__global__ __launch_bounds__(256)
void kA1(const u32* __restrict__ gFp, const int* __restrict__ clu_g,
         const int* __restrict__ clu_s, const float* __restrict__ cf2,
         const u16* __restrict__ WPK, const float* __restrict__ BIAS,
         u32* __restrict__ gFo, int* __restrict__ gSeg) {
    __shared__ __attribute__((aligned(16))) u16 sWS[4][16 * SCR_STRIDE];
    __shared__ int sSeg[SEGSZ];
    __shared__ int sCluW[4][16];
    const int t = threadIdx.x, lane = t & 63, w = t >> 6;
    const int lp = lane & 15, q = lane >> 4;
    const int b = blockIdx.y;
    const size_t bN = (size_t)b * N_;
    u16* scr = sWS[w];
    for (int i = t; i < SEGSZ; i += 256) sSeg[i] = 0;
    __syncthreads();

    for (int s = 0; s < 8; ++s) {
        const int pbase = (blockIdx.x * 8 + s) * 64 + w * 16;
        for (int i = lane; i < 1024; i += 64) {
            int pt = i >> 6, c2 = i & 63;
            *(u32*)(scr + pt * SCR_STRIDE + c2 * 2) = gFp[(bN + pbase + pt) * 64 + c2];
        }
        const int myclu0 = clu_g[bN + pbase + lp];
        const int myclu1 = clu_s[bN + pbase + lp];
        if (q == 0) sCluW[w][lp] = myclu0;
        // f256 = [relu(w3.f128 + b3) ; gather(cf2_0)]
        f32x4 a8[8] = {};
        mlayer<8, 4>(WPK + PK_W3, scr, lane, a8);
        storeAct<8>(scr, BIAS + OB3, lane, a8);
        for (int i = lane; i < 2048; i += 64) {
            int pt = i >> 7, m = i & 127;
            scr[pt * SCR_STRIDE + 128 + m] =
                f2b(cf2[((size_t)b * 32 + sCluW[w][pt]) * 128 + m]);
        }
        f32x4 a4[4] = {};
        mlayer<4, 8>(WPK + PK_W1 + 16384, scr, lane, a4);
        storeAct<4>(scr, BIAS + OB1 + 64, lane, a4);
        f32x4 b8[8] = {};
        mlayer<8, 2>(WPK + PK_W2 + 8192, scr, lane, b8);
        storeActSeg<8>(scr, BIAS + OB2 + 128, lane, b8, sSeg, myclu1);
        for (int i = lane; i < 1024; i += 64) {
            int pt = i >> 6, c2 = i & 63;
            gFo[(bN + pbase + pt) * 64 + c2] = *(const u32*)(scr + pt * SCR_STRIDE + c2 * 2);
        }
        f32x4 c8[8] = {};
        mlayer<8, 4>(WPK + PK_WC1 + 16384, scr, lane, c8);
        storeAct<8>(scr, BIAS + OBC1 + 128, lane, c8);
        f32x4 c16[16] = {};
        mlayer<16, 4>(WPK + PK_WC2 + 32768, scr, lane, c16);
        storeAct<16>(scr, BIAS + OBC2 + 256, lane, c16);
        f32x4 r2[2] = {};
        mlayer<2, 8>(WPK + PK_WC3 + 8192, scr, lane, r2);
        corrAtomic<2>(BIAS + OBC3 + 32, lane, r2, sSeg, myclu1);
    }
    __syncthreads();
    for (int i = t; i < SEGSZ; i += 256) atomicMax(&gSeg[b * SEGSZ + i], sSeg[i]);
}

// ---------- final conv head + per-channel max over points ----------
__global__ __launch_bounds__(256)
void kC(const u32* __restrict__ gFp, const int* __restrict__ clu_g,
        const float* __restrict__ cf2,
        const u16* __restrict__ WPK, const float* __restrict__ BIAS,
        int* __restrict__ gNet) {
    __shared__ __attribute__((aligned(16))) u16 sWS[4][16 * SCR_STRIDE];
    __shared__ int sNet[128];
    __shared__ int sCluW[4][16];
    const int t = threadIdx.x, lane = t & 63, w = t >> 6;
    const int lp = lane & 15, q = lane >> 4;
    const int b = blockIdx.y;
    const size_t bN = (size_t)b * N_;
    u16* scr = sWS[w];
    if (t < 128) sNet[t] = 0;
    __syncthreads();

    for (int s = 0; s < 8; ++s) {
        const int pbase = (blockIdx.x * 8 + s) * 64 + w * 16;
        for (int i = lane; i < 1024; i += 64) {
            int pt = i >> 6, c2 = i & 63;
            *(u32*)(scr + pt * SCR_STRIDE + c2 * 2) = gFp[(bN + pbase + pt) * 64 + c2];
        }
        const int myclu = clu_g[bN + pbase + lp];
        if (q == 0) sCluW[w][lp] = myclu;
        f32x4 a8[8] = {};
        mlayer<8, 4>(WPK + PK_W3 + 16384, scr, lane, a8);
        storeAct<8>(scr, BIAS + OB3 + 128, lane, a8);
        for (int i = lane; i < 2048; i += 64) {
            int pt = i >> 7, m = i & 127;
            scr[pt * SCR_STRIDE + 128 + m] =
                f2b(cf2[((size_t)b * 32 + sCluW[w][pt]) * 128 + m]);
        }
        f32x4 o8[8] = {};
        mlayer<8, 8>(WPK + PK_WO1, scr, lane, o8);
        storeAct<8>(scr, BIAS + OBO1, lane, o8);
        f32x4 p8[8] = {};
        mlayer<8, 4>(WPK + PK_WO2, scr, lane, p8);
#pragma unroll
        for (int tt = 0; tt < 8; ++tt) {
            const int co = tt * 16 + q * 4;
            f32x4 bv = *(const f32x4*)(BIAS + OBO2 + co);
            f32x4 v = p8[tt];
#pragma unroll
            for (int u = 0; u < 4; ++u) {
                float r = fmaxf(v[u] + bv[u], 0.f);
                r = fmaxf(r, __shfl_xor(r, 1, 64));
                r = fmaxf(r, __shfl_xor(r, 2, 64));
                r = fmaxf(r, __shfl_xor(r, 4, 64));
                r = fmaxf(r, __shfl_xor(r, 8, 64));
                if (lp == 0) atomicMax(&sNet[co + u], __float_as_int(r));
            }
        }
    }
    __syncthreads();
    if (t < 128) atomicMax(&gNet[b * 128 + t], sNet[t]);
}

// ---------- tiny MLP head (dual-mode output) ----------
__global__ __launch_bounds__(256)
void kD(const int* __restrict__ gNet, const u16* __restrict__ DWC,
        const float* __restrict__ BIAS, void* __restrict__ outv,
        const int* __restrict__ modep) {
    __shared__ float sN[1024];
    __shared__ float sD1[2048];
    __shared__ float sD2[2048];
    const int mode = *modep;
    const int t = threadIdx.x;
    for (int i = t; i < 1024; i += 256) sN[i] = __int_as_float(gNet[i]);
    __syncthreads();
    for (int i = t; i < 2048; i += 256) {
        int bb = i >> 8, o = i & 255;
        float s = BIAS[ODB1 + o];
        for (int k = 0; k < 128; ++k)
            s = fmaf(sN[bb * 128 + k], b2f(DWC[ODW1 + k * 256 + o]), s);
        sD1[i] = (s >= 0.f) ? s : 0.2f * s;
    }
    __syncthreads();
    for (int i = t; i < 2048; i += 256) {
        int bb = i >> 8, o = i & 255;
        float s = BIAS[ODB2 + o];
        for (int k = 0; k < 256; ++k)
            s = fmaf(sD1[bb * 256 + k], b2f(DWC[ODW2 + k * 256 + o]), s);
        sD2[i] = (s >= 0.f) ? s : 0.2f * s;
    }
    __syncthreads();
    for (int i = t; i < 320; i += 256) {
        int bb = i / 40, o = i - bb * 40;
        float s = BIAS[ODB3 + o];
        for (int k = 0; k < 256; ++k)
            s = fmaf(sD2[bb * 256 + k], b2f(DWC[ODW3 + k * 40 + o]), s);
        if (mode) ((float*)outv)[i] = s;
        else      ((u16*)outv)[i]   = f2b(s);
    }
}

extern "C" void kernel_launch(void* const* d_in, const int* in_sizes, int n_in,
                              void* d_out, int out_size, void* d_ws, size_t ws_size,
                              hipStream_t stream) {
    const void* feat = d_in[0];
    const int* clus = (const int*)d_in[1];

    char* ws = (char*)d_ws;
    u16*   WPK   = (u16*)(ws + OFS_WPK);
    float* BIAS  = (float*)(ws + OFS_BIAS);
    u16*   DWC   = (u16*)(ws + OFS_DWC);
    int*   modep = (int*)(ws + OFS_MODE);
    u16*   FEATC = (u16*)(ws + OFS_FEATC);
    int*   seg0  = (int*)(ws + OFS_GACC0);
    int*   seg1  = (int*)(ws + OFS_GACC1);
    int*   gNet  = (int*)(ws + OFS_GNET);
    float* cf20  = (float*)(ws + OFS_CF20);
    float* cf21  = (float*)(ws + OFS_CF21);
    u32*   f0    = (u32*)(ws + OFS_F0);
    u32*   f1    = (u32*)(ws + OFS_F1);

    hipMemsetAsync(ws + OFS_GACC0, 0, GACC_ZERO_BYTES, stream);
    hipLaunchKernelGGL(kSniff, dim3(1), dim3(256), 0, stream, (const u16*)feat, modep);
    hipLaunchKernelGGL(kPrep, dim3(256), dim3(256), 0, stream,
                       feat, d_in[2], d_in[3], d_in[4], d_in[5], d_in[6], d_in[7],
                       d_in[8], d_in[9], d_in[10], d_in[11], d_in[12], d_in[13],
                       d_in[14], d_in[15], d_in[16], d_in[17], d_in[18], d_in[19],
                       d_in[20], d_in[21], d_in[22], d_in[23], d_in[24], d_in[25],
                       WPK, BIAS, DWC, FEATC, modep);

    const int* clu0 = clus;
    const int* clu1 = clus + (size_t)B_ * N_;
    dim3 blk(256);

    hipLaunchKernelGGL(kA0, dim3(64, 8), blk, 0, stream,
                       FEATC, clu0, WPK, BIAS, f0, seg0);
    hipLaunchKernelGGL(kB, dim3(8), blk, 0, stream, seg0, cf20);
    hipLaunchKernelGGL(kA1, dim3(64, 8), blk, 0, stream,
                       f0, clu0, clu1, cf20, WPK, BIAS, f1, seg1);
    hipLaunchKernelGGL(kB, dim3(8), blk, 0, stream, seg1, cf21);
    hipLaunchKernelGGL(kC, dim3(64, 8), blk, 0, stream,
                       f1, clu1, cf21, WPK, BIAS, gNet);
    hipLaunchKernelGGL(kD, dim3(1), blk, 0, stream,
                       gNet, DWC, BIAS, d_out, modep);
}

// Round 5
// 1006.665 us; speedup vs baseline: 2.4724x; 2.4724x over previous
//
#include <hip/hip_runtime.h>
#include <stdint.h>

// Problem constants
#define B_   8
#define N_   32768
#define C_   32
#define K_   22
#define CAT_ 40

typedef unsigned short u16;
typedef unsigned int   u32;

typedef __attribute__((ext_vector_type(8))) short bf16x8;
typedef __attribute__((ext_vector_type(4))) float f32x4;

#define MFMA(a, b, c) __builtin_amdgcn_mfma_f32_16x16x32_bf16(a, b, c, 0, 0, 0)

// ---------- bf16 helpers (raw bits) ----------
__device__ __forceinline__ float b2f(u16 v) { return __uint_as_float(((u32)v) << 16); }
__device__ __forceinline__ u16 f2b(float f) {
    u32 x = __float_as_uint(f);
    return (u16)((x + 0x7fffu + ((x >> 16) & 1u)) >> 16);   // RNE
}
__device__ __forceinline__ u32 pk2(float a, float b) {
    return (u32)f2b(a) | ((u32)f2b(b) << 16);
}

// ---------- packed MFMA A-fragment weight offsets (u16 units) ----------
#define PK_WIN 0
#define PK_W1  8192
#define PK_W2  40960
#define PK_W3  57344
#define PK_WC1 90112
#define PK_WC2 122880
#define PK_WC3 188416
#define PK_WO1 204800
#define PK_WO2 237568

// ---------- fp32 bias block offsets (floats) ----------
#define OBIN 0
#define OB1  256
#define OB2  384
#define OB3  640
#define OBC1 896
#define OBC2 1152
#define OBC3 1664
#define OBO1 1728
#define OBO2 1856
#define ODB1 1984
#define ODB2 2240
#define ODB3 2496

// ---------- canonical bf16 dense-head weights (u16 offsets) ----------
#define ODW1 0
#define ODW2 32768
#define ODW3 98304

// ---------- segment accumulator geometry ----------
#define SEGW 164
#define SEGSZ (32 * SEGW)

// ---------- workspace byte offsets ----------
#define OFS_WPK   0u
#define OFS_BIAS  524288u
#define OFS_DWC   540672u
#define OFS_MODE  786432u
#define OFS_FEATC 1048576u
#define OFS_GACC0 12582912u
#define OFS_GACC1 (OFS_GACC0 + 4u*SEGSZ*8u)
#define OFS_GNET  (OFS_GACC1 + 4u*SEGSZ*8u)
#define GACC_ZERO_BYTES (4u*SEGSZ*8u*2u + 4096u)
#define OFS_CF20  13107200u
#define OFS_CF21  13238272u
#define OFS_F0    16777216u
#define OFS_F1    83886080u
// end = 150,994,944 bytes

// ---------- dtype sniffer ----------
__global__ void kSniff(const u16* __restrict__ featAny, int* __restrict__ mode) {
    __shared__ int cnt;
    if (threadIdx.x == 0) cnt = 0;
    __syncthreads();
    int weird = 0;
    for (int j = 0; j < 4; ++j) {
        u16 v = featAny[threadIdx.x * 4 + j];
        float f = b2f(v);
        if (v == 0 || !(fabsf(f) < 1e10f)) weird++;
    }
    if (weird) atomicAdd(&cnt, weird);
    __syncthreads();
    if (threadIdx.x == 0) *mode = (cnt > 64) ? 1 : 0;
}

__device__ __forceinline__ float fetchF(const void* src, size_t i, int mode) {
    return mode ? ((const float*)src)[i] : b2f(((const u16*)src)[i]);
}

// ---------- weight pack: (COUT,CIN) -> MFMA A-fragment bf16 order ----------
__device__ void packA(const void* __restrict__ src, u16* __restrict__ dst,
                      int COUT, int CIN, int mode, int tid, int np) {
    int KB = (CIN + 31) / 32;
    int tiles = COUT / 16;
    int tot = tiles * KB * 64 * 8;
    for (int i = tid; i < tot; i += np) {
        int j = i & 7;
        int L = (i >> 3) & 63;
        int rest = i >> 9;
        int kb = rest % KB, tile = rest / KB;
        int co = tile * 16 + (L & 15);
        int ci = kb * 32 + (L >> 4) * 8 + j;
        float v = (ci < CIN) ? fetchF(src, (size_t)co * CIN + ci, mode) : 0.f;
        dst[i] = f2b(v);
    }
}

__device__ void cvtF(const void* __restrict__ src, float* __restrict__ dst,
                     int n, int mode, int tid, int np) {
    for (int i = tid; i < n; i += np) dst[i] = fetchF(src, i, mode);
}

__device__ void cvtB(const void* __restrict__ src, u16* __restrict__ dst,
                     int n, int mode, int tid, int np) {
    for (int i = tid; i < n; i += np)
        dst[i] = mode ? f2b(((const float*)src)[i]) : ((const u16*)src)[i];
}

__global__ void kPrep(const void* feat, const void* w_in, const void* b_in,
                      const void* w1, const void* b1, const void* w2, const void* b2,
                      const void* w3, const void* b3,
                      const void* wc1, const void* bc1, const void* wc2, const void* bc2,
                      const void* wc3, const void* bc3,
                      const void* wo1, const void* bo1, const void* wo2, const void* bo2,
                      const void* dw1, const void* db1, const void* dw2, const void* db2,
                      const void* dw3, const void* db3,
                      u16* WPK, float* BIAS, u16* DWC, u16* FEATC,
                      const int* __restrict__ modep) {
    const int mode = *modep;
    int tid = blockIdx.x * blockDim.x + threadIdx.x;
    int np  = gridDim.x * blockDim.x;
    cvtB(feat, FEATC, B_ * N_ * K_, mode, tid, np);
    packA(w_in, WPK + PK_WIN, 256, 22, mode, tid, np);
    packA(w1,                                  WPK + PK_W1,          64, 256, mode, tid, np);
    packA((const u16*)w1 + (mode?32768:16384), WPK + PK_W1 + 16384,  64, 256, mode, tid, np);
    packA(w2,                                  WPK + PK_W2,          128, 64, mode, tid, np);
    packA((const u16*)w2 + (mode?16384:8192),  WPK + PK_W2 + 8192,   128, 64, mode, tid, np);
    packA(w3,                                  WPK + PK_W3,          128, 128, mode, tid, np);
    packA((const u16*)w3 + (mode?32768:16384), WPK + PK_W3 + 16384,  128, 128, mode, tid, np);
    packA(wc1,                                 WPK + PK_WC1,         128, 128, mode, tid, np);
    packA((const u16*)wc1 + (mode?32768:16384),WPK + PK_WC1 + 16384, 128, 128, mode, tid, np);
    packA(wc2,                                 WPK + PK_WC2,         256, 128, mode, tid, np);
    packA((const u16*)wc2 + (mode?65536:32768),WPK + PK_WC2 + 32768, 256, 128, mode, tid, np);
    packA(wc3,                                 WPK + PK_WC3,         32, 256, mode, tid, np);
    packA((const u16*)wc3 + (mode?16384:8192), WPK + PK_WC3 + 8192,  32, 256, mode, tid, np);
    packA(wo1, WPK + PK_WO1, 128, 256, mode, tid, np);
    packA(wo2, WPK + PK_WO2, 128, 128, mode, tid, np);
    cvtF(b_in, BIAS + OBIN, 256, mode, tid, np);
    cvtF(b1,   BIAS + OB1,  128, mode, tid, np);
    cvtF(b2,   BIAS + OB2,  256, mode, tid, np);
    cvtF(b3,   BIAS + OB3,  256, mode, tid, np);
    cvtF(bc1,  BIAS + OBC1, 256, mode, tid, np);
    cvtF(bc2,  BIAS + OBC2, 512, mode, tid, np);
    cvtF(bc3,  BIAS + OBC3, 64,  mode, tid, np);
    cvtF(bo1,  BIAS + OBO1, 128, mode, tid, np);
    cvtF(bo2,  BIAS + OBO2, 128, mode, tid, np);
    cvtF(db1,  BIAS + ODB1, 256, mode, tid, np);
    cvtF(db2,  BIAS + ODB2, 256, mode, tid, np);
    cvtF(db3,  BIAS + ODB3, 40,  mode, tid, np);
    cvtB(dw1, DWC + ODW1, 128 * 256, mode, tid, np);
    cvtB(dw2, DWC + ODW2, 256 * 256, mode, tid, np);
    cvtB(dw3, DWC + ODW3, 256 * 40,  mode, tid, np);
}

// ================= MFMA conv building blocks (64-pt tile, 4 waves) =================
template<int CIN, int INS, int OUTS, bool NETMAX = false>
__device__ __forceinline__ void mconv128(const u16* __restrict__ wA, const float* __restrict__ bias,
                                         const u16* __restrict__ sIn, u16* __restrict__ sOut,
                                         int* __restrict__ sNet) {
    const int t = threadIdx.x;
    const int lane = t & 63, w = t >> 6, lp = lane & 15, q = lane >> 4;
    constexpr int KB = CIN / 32;
    f32x4 acc[2][4] = {};
#pragma unroll
    for (int kb = 0; kb < KB; ++kb) {
        bf16x8 a0 = *(const bf16x8*)(wA + (size_t)(((w * 2 + 0) * KB + kb) * 64 + lane) * 8);
        bf16x8 a1 = *(const bf16x8*)(wA + (size_t)(((w * 2 + 1) * KB + kb) * 64 + lane) * 8);
        bf16x8 bb[4];
#pragma unroll
        for (int pt = 0; pt < 4; ++pt)
            bb[pt] = *(const bf16x8*)(sIn + (pt * 16 + lp) * INS + kb * 32 + q * 8);
#pragma unroll
        for (int pt = 0; pt < 4; ++pt) {
            acc[0][pt] = MFMA(a0, bb[pt], acc[0][pt]);
            acc[1][pt] = MFMA(a1, bb[pt], acc[1][pt]);
        }
    }
#pragma unroll
    for (int ct = 0; ct < 2; ++ct) {
        const int co = (w * 2 + ct) * 16 + q * 4;
        f32x4 bv = *(const f32x4*)(bias + co);
#pragma unroll
        for (int pt = 0; pt < 4; ++pt) {
            f32x4 v = acc[ct][pt];
            float r0 = fmaxf(v[0] + bv[0], 0.f), r1 = fmaxf(v[1] + bv[1], 0.f);
            float r2 = fmaxf(v[2] + bv[2], 0.f), r3 = fmaxf(v[3] + bv[3], 0.f);
            if constexpr (NETMAX) {
                atomicMax(&sNet[co + 0], __float_as_int(r0));
                atomicMax(&sNet[co + 1], __float_as_int(r1));
                atomicMax(&sNet[co + 2], __float_as_int(r2));
                atomicMax(&sNet[co + 3], __float_as_int(r3));
            } else {
                const int p = pt * 16 + lp;
                *(uint2*)(sOut + p * OUTS + co) = make_uint2(pk2(r0, r1), pk2(r2, r3));
            }
        }
    }
}

template<int CIN, int INS>
__device__ __forceinline__ void mchunk_prod(const u16* __restrict__ wA, const float* __restrict__ bias,
                                            int c, const u16* __restrict__ sIn, u16* __restrict__ sCh) {
    const int t = threadIdx.x;
    const int lane = t & 63, w = t >> 6, lp = lane & 15, q = lane >> 4;
    constexpr int KB = CIN / 32;
    const int ct = w & 1, pp = (w >> 1) * 2;
    f32x4 acc[2] = {};
#pragma unroll
    for (int kb = 0; kb < KB; ++kb) {
        bf16x8 a  = *(const bf16x8*)(wA + (size_t)(((2 * c + ct) * KB + kb) * 64 + lane) * 8);
        bf16x8 b0 = *(const bf16x8*)(sIn + ((pp + 0) * 16 + lp) * INS + kb * 32 + q * 8);
        bf16x8 b1 = *(const bf16x8*)(sIn + ((pp + 1) * 16 + lp) * INS + kb * 32 + q * 8);
        acc[0] = MFMA(a, b0, acc[0]);
        acc[1] = MFMA(a, b1, acc[1]);
    }
    const int col = ct * 16 + q * 4;
    f32x4 bv = *(const f32x4*)(bias + 32 * c + col);
#pragma unroll
    for (int i = 0; i < 2; ++i) {
        f32x4 v = acc[i];
        const int p = (pp + i) * 16 + lp;
        *(uint2*)(sCh + p * 40 + col) =
            make_uint2(pk2(fmaxf(v[0] + bv[0], 0.f), fmaxf(v[1] + bv[1], 0.f)),
                       pk2(fmaxf(v[2] + bv[2], 0.f), fmaxf(v[3] + bv[3], 0.f)));
    }
}

template<int CT>
__device__ __forceinline__ void mchunk_cons(const u16* __restrict__ wA, int ctBase, int c,
                                            const u16* __restrict__ sCh, f32x4 (&acc)[CT][4]) {
    const int t = threadIdx.x;
    const int lane = t & 63, lp = lane & 15, q = lane >> 4;
    bf16x8 bb[4];
#pragma unroll
    for (int pt = 0; pt < 4; ++pt)
        bb[pt] = *(const bf16x8*)(sCh + (pt * 16 + lp) * 40 + q * 8);
#pragma unroll
    for (int k = 0; k < CT; ++k) {
        bf16x8 a = *(const bf16x8*)(wA + (size_t)(((ctBase + k) * 8 + c) * 64 + lane) * 8);
#pragma unroll
        for (int pt = 0; pt < 4; ++pt)
            acc[k][pt] = MFMA(a, bb[pt], acc[k][pt]);
    }
}

__device__ __forceinline__ void mcorr_cons(const u16* __restrict__ wA, int c,
                                           const u16* __restrict__ sCh, f32x4 (&acc)[2]) {
    const int t = threadIdx.x;
    const int lane = t & 63, w = t >> 6, lp = lane & 15, q = lane >> 4;
    const int ct = w & 1, pp = (w >> 1) * 2;
    bf16x8 a  = *(const bf16x8*)(wA + (size_t)((ct * 8 + c) * 64 + lane) * 8);
    bf16x8 b0 = *(const bf16x8*)(sCh + ((pp + 0) * 16 + lp) * 40 + q * 8);
    bf16x8 b1 = *(const bf16x8*)(sCh + ((pp + 1) * 16 + lp) * 40 + q * 8);
    acc[0] = MFMA(a, b0, acc[0]);
    acc[1] = MFMA(a, b1, acc[1]);
}

// corr output -> LDS corr-only segmax (32 clusters x 36-padded)
__device__ __forceinline__ void corrAtomicC(const float* __restrict__ bias, int lane, int w,
                                            f32x4 (&acc)[2], int* __restrict__ sSegC,
                                            const int* __restrict__ sClu) {
    const int lp = lane & 15, q = lane >> 4;
    const int ct = w & 1, pp = (w >> 1) * 2;
    const int col = ct * 16 + q * 4;
    f32x4 bv = *(const f32x4*)(bias + col);
#pragma unroll
    for (int i = 0; i < 2; ++i) {
        const int p = (pp + i) * 16 + lp;
        const int cl = sClu[p];
        f32x4 v = acc[i];
        atomicMax(&sSegC[cl * 36 + col + 0], __float_as_int(fmaxf(v[0] + bv[0], 0.f)));
        atomicMax(&sSegC[cl * 36 + col + 1], __float_as_int(fmaxf(v[1] + bv[1], 0.f)));
        atomicMax(&sSegC[cl * 36 + col + 2], __float_as_int(fmaxf(v[2] + bv[2], 0.f)));
        atomicMax(&sSegC[cl * 36 + col + 3], __float_as_int(fmaxf(v[3] + bv[3], 0.f)));
    }
}

// ---------- iteration-0 fused kernel ----------
__global__ __launch_bounds__(256)
void kA0(const u16* __restrict__ featc, const int* __restrict__ clu0,
         const u16* __restrict__ WPK, const float* __restrict__ BIAS,
         u32* __restrict__ gF, int* __restrict__ gSeg) {
    __shared__ __attribute__((aligned(16))) u16 R1[64 * 136];   // feat(40) -> h(72) -> c1(136)
    __shared__ __attribute__((aligned(16))) u16 sCh[2][64 * 40];
    __shared__ __attribute__((aligned(16))) u16 sF[64 * 136];
    __shared__ int sSegC[32 * 36];
    __shared__ int sClu[64];
    const int t = threadIdx.x, lane = t & 63, w = t >> 6;
    const int lp = lane & 15, q = lane >> 4;
    const int b = blockIdx.y;
    const size_t bN = (size_t)b * N_;
    for (int i = t; i < 1152; i += 256) sSegC[i] = 0;

    for (int s = 0; s < 2; ++s) {
        const int n0 = (blockIdx.x * 2 + s) * 64;
        for (int i = t; i < 2560; i += 256) {
            int pt = i / 40, k = i - pt * 40;
            R1[i] = (k < 22) ? featc[(bN + n0 + pt) * 22 + k] : (u16)0;
        }
        if (t < 64) sClu[t] = clu0[bN + n0 + t];
        __syncthreads();
        f32x4 hacc[1][4] = {};
        for (int c = 0; c < 8; ++c) {
            mchunk_prod<32, 40>(WPK + PK_WIN, BIAS + OBIN, c, R1, sCh[c & 1]);
            __syncthreads();
            mchunk_cons<1>(WPK + PK_W1, w, c, sCh[c & 1], hacc);
        }
        {   const int co = w * 16 + q * 4;
            f32x4 bv = *(const f32x4*)(BIAS + OB1 + co);
#pragma unroll
            for (int pt = 0; pt < 4; ++pt) {
                f32x4 v = hacc[0][pt];
                int p = pt * 16 + lp;
                *(uint2*)(R1 + p * 72 + co) =
                    make_uint2(pk2(fmaxf(v[0] + bv[0], 0.f), fmaxf(v[1] + bv[1], 0.f)),
                               pk2(fmaxf(v[2] + bv[2], 0.f), fmaxf(v[3] + bv[3], 0.f)));
            }
        }
        __syncthreads();
        mconv128<64, 72, 136>(WPK + PK_W2, BIAS + OB2, R1, sF, nullptr);
        __syncthreads();
        for (int i = t; i < 4096; i += 256) {
            int pt = i >> 6, c2 = i & 63;
            gF[(bN + n0 + pt) * 64 + c2] = *(const u32*)(sF + pt * 136 + c2 * 2);
        }
        mconv128<128, 136, 136>(WPK + PK_WC1, BIAS + OBC1, sF, R1, nullptr);
        __syncthreads();
        f32x4 cacc[2] = {};
        for (int c = 0; c < 8; ++c) {
            mchunk_prod<128, 136>(WPK + PK_WC2, BIAS + OBC2, c, R1, sCh[c & 1]);
            __syncthreads();
            mcorr_cons(WPK + PK_WC3, c, sCh[c & 1], cacc);
        }
        corrAtomicC(BIAS + OBC3, lane, w, cacc, sSegC, sClu);
        __syncthreads();
    }
    for (int i = t; i < 1024; i += 256) {
        int clu = i >> 5, ch = i & 31;
        int v = sSegC[clu * 36 + ch];
        if (v) atomicMax(&gSeg[b * SEGSZ + clu * SEGW + 128 + ch], v);
    }
}

// ---------- f128 segment-max kernel (memory-bound, high occupancy) ----------
__global__ __launch_bounds__(256)
void kS(const u32* __restrict__ fX, const int* __restrict__ cluX, int* __restrict__ gSeg) {
    __shared__ int sSeg[SEGSZ];
    __shared__ int sClu[512];
    const int t = threadIdx.x, b = blockIdx.y;
    const size_t bN = (size_t)b * N_;
    const int p0 = blockIdx.x * 512;
    for (int i = t; i < SEGSZ; i += 256) sSeg[i] = 0;
    for (int i = t; i < 512; i += 256) sClu[i] = cluX[bN + p0 + i];
    __syncthreads();
    for (int i = t; i < 512 * 64; i += 256) {
        int pt = i >> 6, d = i & 63;
        u32 v = fX[(bN + p0 + pt) * 64 + d];
        int base = sClu[pt] * SEGW + d * 2;
        atomicMax(&sSeg[base + 0], __float_as_int(b2f((u16)v)));
        atomicMax(&sSeg[base + 1], __float_as_int(b2f((u16)(v >> 16))));
    }
    __syncthreads();
    for (int i = t; i < 32 * 128; i += 256) {
        int clu = i >> 7, ch = i & 127;
        int v = sSeg[clu * SEGW + ch];
        if (v) atomicMax(&gSeg[b * SEGSZ + clu * SEGW + ch], v);
    }
}

// ---------- per-batch cluster math: cf2[b][c][ch] ----------
__global__ __launch_bounds__(256)
void kB(const int* __restrict__ gSeg, float* __restrict__ cf2) {
    __shared__ float sA[SEGSZ];
    __shared__ float sR[1024];
    __shared__ float sI[32];
    const int t = threadIdx.x, b = blockIdx.x;
    for (int i = t; i < SEGSZ; i += 256) sA[i] = __int_as_float(gSeg[b * SEGSZ + i]);
    __syncthreads();
    if (t < 32) {
        float s = 0.f;
        for (int j = 0; j < 32; ++j) { float v = sA[t * SEGW + 128 + j]; s = fmaf(v, v, s); }
        sI[t] = 1.f / fmaxf(sqrtf(s), 1e-12f);
    }
    __syncthreads();
    for (int i = t; i < 1024; i += 256) {
        int ca = i >> 5, cb = i & 31;
        float s = 0.f;
        for (int j = 0; j < 32; ++j)
            s = fmaf(sA[ca * SEGW + 128 + j], sA[cb * SEGW + 128 + j], s);
        sR[i] = s * sI[ca] * sI[cb];
    }
    __syncthreads();
    for (int i = t; i < 4096; i += 256) {
        int c = i >> 7, ch = i & 127;
        float s = 0.f;
        for (int cp = 0; cp < 32; ++cp)
            s = fmaf(sA[cp * SEGW + ch], sR[cp * 32 + c], s);
        cf2[((size_t)b * 32 + c) * 128 + ch] = s;
    }
}

// ---------- iteration-1 fused kernel ----------
__global__ __launch_bounds__(256)
void kA1(const u32* __restrict__ gFp, const int* __restrict__ clu_g,
         const int* __restrict__ clu_s, const float* __restrict__ cf2,
         const u16* __restrict__ WPK, const float* __restrict__ BIAS,
         u32* __restrict__ gFo, int* __restrict__ gSeg) {
    __shared__ __attribute__((aligned(16))) u16 R1[64 * 136];   // f128in -> h(72) -> c1
    __shared__ __attribute__((aligned(16))) u16 sCh[2][64 * 40];
    __shared__ __attribute__((aligned(16))) u16 sF[64 * 136];
    __shared__ int sSegC[32 * 36];
    __shared__ int sClu0[64];
    __shared__ int sClu1[64];
    const int t = threadIdx.x, lane = t & 63, w = t >> 6;
    const int lp = lane & 15, q = lane >> 4;
    const int b = blockIdx.y;
    const size_t bN = (size_t)b * N_;
    for (int i = t; i < 1152; i += 256) sSegC[i] = 0;

    for (int s = 0; s < 2; ++s) {
        const int n0 = (blockIdx.x * 2 + s) * 64;
        for (int i = t; i < 4096; i += 256) {
            int pt = i >> 6, c2 = i & 63;
            *(u32*)(R1 + pt * 136 + c2 * 2) = gFp[(bN + n0 + pt) * 64 + c2];
        }
        if (t < 64) sClu0[t] = clu_g[bN + n0 + t];
        else if (t < 128) sClu1[t - 64] = clu_s[bN + n0 + (t - 64)];
        __syncthreads();
        f32x4 hacc[1][4] = {};
        for (int c = 0; c < 8; ++c) {
            if (c < 4) {
                mchunk_prod<128, 136>(WPK + PK_W3, BIAS + OB3, c, R1, sCh[c & 1]);
            } else {
                for (int i = t; i < 2048; i += 256) {
                    int pt = i >> 5, m = i & 31;
                    sCh[c & 1][pt * 40 + m] =
                        f2b(cf2[((size_t)b * 32 + sClu0[pt]) * 128 + (c - 4) * 32 + m]);
                }
            }
            __syncthreads();
            mchunk_cons<1>(WPK + PK_W1 + 16384, w, c, sCh[c & 1], hacc);
        }
        {   const int co = w * 16 + q * 4;
            f32x4 bv = *(const f32x4*)(BIAS + OB1 + 64 + co);
#pragma unroll
            for (int pt = 0; pt < 4; ++pt) {
                f32x4 v = hacc[0][pt];
                int p = pt * 16 + lp;
                *(uint2*)(R1 + p * 72 + co) =
                    make_uint2(pk2(fmaxf(v[0] + bv[0], 0.f), fmaxf(v[1] + bv[1], 0.f)),
                               pk2(fmaxf(v[2] + bv[2], 0.f), fmaxf(v[3] + bv[3], 0.f)));
            }
        }
        __syncthreads();
        mconv128<64, 72, 136>(WPK + PK_W2 + 8192, BIAS + OB2 + 128, R1, sF, nullptr);
        __syncthreads();
        for (int i = t; i < 4096; i += 256) {
            int pt = i >> 6, c2 = i & 63;
            gFo[(bN + n0 + pt) * 64 + c2] = *(const u32*)(sF + pt * 136 + c2 * 2);
        }
        mconv128<128, 136, 136>(WPK + PK_WC1 + 16384, BIAS + OBC1 + 128, sF, R1, nullptr);
        __syncthreads();
        f32x4 cacc[2] = {};
        for (int c = 0; c < 8; ++c) {
            mchunk_prod<128, 136>(WPK + PK_WC2 + 32768, BIAS + OBC2 + 256, c, R1, sCh[c & 1]);
            __syncthreads();
            mcorr_cons(WPK + PK_WC3 + 8192, c, sCh[c & 1], cacc);
        }
        corrAtomicC(BIAS + OBC3 + 32, lane, w, cacc, sSegC, sClu1);
        __syncthreads();
    }
    for (int i = t; i < 1024; i += 256) {
        int clu = i >> 5, ch = i & 31;
        int v = sSegC[clu * 36 + ch];
        if (v) atomicMax(&gSeg[b * SEGSZ + clu * SEGW + 128 + ch], v);
    }
}

// ---------- final conv head + per-channel max over points ----------
__global__ __launch_bounds__(256)
void kC(const u32* __restrict__ gFp, const int* __restrict__ clu_g,
        const float* __restrict__ cf2,
        const u16* __restrict__ WPK, const float* __restrict__ BIAS,
        int* __restrict__ gNet) {
    __shared__ __attribute__((aligned(16))) u16 R1[64 * 136];   // f128in -> o1
    __shared__ __attribute__((aligned(16))) u16 sCh[2][64 * 40];
    __shared__ int sNet[128];
    __shared__ int sClu[64];
    const int t = threadIdx.x, lane = t & 63, w = t >> 6;
    const int lp = lane & 15, q = lane >> 4;
    const int b = blockIdx.y;
    const size_t bN = (size_t)b * N_;
    if (t < 128) sNet[t] = 0;

    for (int s = 0; s < 2; ++s) {
        const int n0 = (blockIdx.x * 2 + s) * 64;
        for (int i = t; i < 4096; i += 256) {
            int pt = i >> 6, c2 = i & 63;
            *(u32*)(R1 + pt * 136 + c2 * 2) = gFp[(bN + n0 + pt) * 64 + c2];
        }
        if (t < 64) sClu[t] = clu_g[bN + n0 + t];
        __syncthreads();
        f32x4 oacc[2][4] = {};
        for (int c = 0; c < 8; ++c) {
            if (c < 4) {
                mchunk_prod<128, 136>(WPK + PK_W3 + 16384, BIAS + OB3 + 128, c, R1, sCh[c & 1]);
            } else {
                for (int i = t; i < 2048; i += 256) {
                    int pt = i >> 5, m = i & 31;
                    sCh[c & 1][pt * 40 + m] =
                        f2b(cf2[((size_t)b * 32 + sClu[pt]) * 128 + (c - 4) * 32 + m]);
                }
            }
            __syncthreads();
            mchunk_cons<2>(WPK + PK_WO1, 2 * w, c, sCh[c & 1], oacc);
        }
#pragma unroll
        for (int ct = 0; ct < 2; ++ct) {
            const int co = (2 * w + ct) * 16 + q * 4;
            f32x4 bv = *(const f32x4*)(BIAS + OBO1 + co);
#pragma unroll
            for (int pt = 0; pt < 4; ++pt) {
                f32x4 v = oacc[ct][pt];
                int p = pt * 16 + lp;
                *(uint2*)(R1 + p * 136 + co) =
                    make_uint2(pk2(fmaxf(v[0] + bv[0], 0.f), fmaxf(v[1] + bv[1], 0.f)),
                               pk2(fmaxf(v[2] + bv[2], 0.f), fmaxf(v[3] + bv[3], 0.f)));
            }
        }
        __syncthreads();
        mconv128<128, 136, 136, true>(WPK + PK_WO2, BIAS + OBO2, R1, nullptr, sNet);
        __syncthreads();
    }
    if (t < 128) atomicMax(&gNet[b * 128 + t], sNet[t]);
}

// ---------- tiny MLP head (dual-mode output) ----------
__global__ __launch_bounds__(256)
void kD(const int* __restrict__ gNet, const u16* __restrict__ DWC,
        const float* __restrict__ BIAS, void* __restrict__ outv,
        const int* __restrict__ modep) {
    __shared__ float sN[1024];
    __shared__ float sD1[2048];
    __shared__ float sD2[2048];
    const int mode = *modep;
    const int t = threadIdx.x;
    for (int i = t; i < 1024; i += 256) sN[i] = __int_as_float(gNet[i]);
    __syncthreads();
    for (int i = t; i < 2048; i += 256) {
        int bb = i >> 8, o = i & 255;
        float s = BIAS[ODB1 + o];
        for (int k = 0; k < 128; ++k)
            s = fmaf(sN[bb * 128 + k], b2f(DWC[ODW1 + k * 256 + o]), s);
        sD1[i] = (s >= 0.f) ? s : 0.2f * s;
    }
    __syncthreads();
    for (int i = t; i < 2048; i += 256) {
        int bb = i >> 8, o = i & 255;
        float s = BIAS[ODB2 + o];
        for (int k = 0; k < 256; ++k)
            s = fmaf(sD1[bb * 256 + k], b2f(DWC[ODW2 + k * 256 + o]), s);
        sD2[i] = (s >= 0.f) ? s : 0.2f * s;
    }
    __syncthreads();
    for (int i = t; i < 320; i += 256) {
        int bb = i / 40, o = i - bb * 40;
        float s = BIAS[ODB3 + o];
        for (int k = 0; k < 256; ++k)
            s = fmaf(sD2[bb * 256 + k], b2f(DWC[ODW3 + k * 40 + o]), s);
        if (mode) ((float*)outv)[i] = s;
        else      ((u16*)outv)[i]   = f2b(s);
    }
}

extern "C" void kernel_launch(void* const* d_in, const int* in_sizes, int n_in,
                              void* d_out, int out_size, void* d_ws, size_t ws_size,
                              hipStream_t stream) {
    const void* feat = d_in[0];
    const int* clus = (const int*)d_in[1];

    char* ws = (char*)d_ws;
    u16*   WPK   = (u16*)(ws + OFS_WPK);
    float* BIAS  = (float*)(ws + OFS_BIAS);
    u16*   DWC   = (u16*)(ws + OFS_DWC);
    int*   modep = (int*)(ws + OFS_MODE);
    u16*   FEATC = (u16*)(ws + OFS_FEATC);
    int*   seg0  = (int*)(ws + OFS_GACC0);
    int*   seg1  = (int*)(ws + OFS_GACC1);
    int*   gNet  = (int*)(ws + OFS_GNET);
    float* cf20  = (float*)(ws + OFS_CF20);
    float* cf21  = (float*)(ws + OFS_CF21);
    u32*   f0    = (u32*)(ws + OFS_F0);
    u32*   f1    = (u32*)(ws + OFS_F1);

    hipMemsetAsync(ws + OFS_GACC0, 0, GACC_ZERO_BYTES, stream);
    hipLaunchKernelGGL(kSniff, dim3(1), dim3(256), 0, stream, (const u16*)feat, modep);
    hipLaunchKernelGGL(kPrep, dim3(256), dim3(256), 0, stream,
                       feat, d_in[2], d_in[3], d_in[4], d_in[5], d_in[6], d_in[7],
                       d_in[8], d_in[9], d_in[10], d_in[11], d_in[12], d_in[13],
                       d_in[14], d_in[15], d_in[16], d_in[17], d_in[18], d_in[19],
                       d_in[20], d_in[21], d_in[22], d_in[23], d_in[24], d_in[25],
                       WPK, BIAS, DWC, FEATC, modep);

    const int* clu0 = clus;
    const int* clu1 = clus + (size_t)B_ * N_;
    dim3 blk(256);

    hipLaunchKernelGGL(kA0, dim3(256, 8), blk, 0, stream,
                       FEATC, clu0, WPK, BIAS, f0, seg0);
    hipLaunchKernelGGL(kS, dim3(64, 8), blk, 0, stream, f0, clu0, seg0);
    hipLaunchKernelGGL(kB, dim3(8), blk, 0, stream, seg0, cf20);
    hipLaunchKernelGGL(kA1, dim3(256, 8), blk, 0, stream,
                       f0, clu0, clu1, cf20, WPK, BIAS, f1, seg1);
    hipLaunchKernelGGL(kS, dim3(64, 8), blk, 0, stream, f1, clu1, seg1);
    hipLaunchKernelGGL(kB, dim3(8), blk, 0, stream, seg1, cf21);
    hipLaunchKernelGGL(kC, dim3(256, 8), blk, 0, stream,
                       f1, clu1, cf21, WPK, BIAS, gNet);
    hipLaunchKernelGGL(kD, dim3(1), blk, 0, stream,
                       gNet, DWC, BIAS, d_out, modep);
}